// Round 10
// baseline (153.122 us; speedup 1.0000x reference)
//
#include <hip/hip_runtime.h>

// DeepFM fused kernel for MI355X (gfx950) — round 10.
// R9 + occupancy-truth for the scheduler: __launch_bounds__(512) +
// amdgpu_waves_per_eu(2,4). R4-R9 all compiled to <=64 VGPRs (8-waves/EU
// pressure target) which serialized the 7 independent loads per kg
// iteration (~3.5k cyc/iter). LDS caps us at 2 blocks/CU = 4 waves/EU, so
// declaring max=4 sacrifices nothing and min=2 raises the register budget;
// the scheduler can now keep a whole iteration's loads in flight.
//  - prep: repack Wm/Wu (augmented: 16 FM col-sum feats + additive feat),
//    W1, W2 into bf16 MFMA A-frag order in ws; bias aux. 256-thr blocks.
//  - main: 512 blocks x 512 thr (8 waves), 32 rows/block, 2 blocks/CU
//    (dynamic LDS 71296 B). Tower-parallel phase 1 (waves 0-3 movie,
//    4-7 user), B staged in two half-K rounds, FM via padded LDS buf.

#define NTH 512
#define RB  32

typedef __bf16 bf16x8 __attribute__((ext_vector_type(8)));
typedef float  f32x4  __attribute__((ext_vector_type(4)));

// workspace layout (bytes)
#define WS_WMF  0            // movie tower A-frags [16 kg][18 ft][64][16B]
#define WS_WUF  294912
#define WS_W1F  589824       // [16 kg][16 ft][64][16B]
#define WS_W2F  851968       // [8 kg][8 ft][64][16B]
#define WS_BIAS 917504       // fp32 bms[16] bus[16] badd

// LDS layout (bytes)
#define BPITCH  528          // 256 bf16 (half K) + 16B pad per row
#define L_BST   0            // bstage: 64 rows x 528 = 33792 (h1frag aliases)
#define L_DENSE 33792        // densefrag [16kg][2rt][64][16] = 32768
#define L_FM    66560        // fmbuf [2][32][17] f32 = 4352 (padded pitch 17)
#define L_ADD   70912        // addbuf [2][32] f32 = 256
#define L_OUT   71168        // outpart[32] f32 = 128
#define LDSB    71296

__device__ __forceinline__ unsigned short f2bf(float f) {
  unsigned u = __builtin_bit_cast(unsigned, f);
  u += 0x7FFFu + ((u >> 16) & 1u);           // RNE
  return (unsigned short)(u >> 16);
}

__device__ __forceinline__ f32x4 mfma_bf16(bf16x8 a, bf16x8 b, f32x4 c) {
  return __builtin_amdgcn_mfma_f32_16x16x32_bf16(a, b, c, 0, 0, 0);
}

// ---------------------------------------------------------------------------
// Prep: fragment-ordered bf16 weights + bias aux. Tower features:
// f<256 raw col f; 256..271 = sum_i W[:, i*16+(f-256)] (FM col sums);
// 272 = W[:,256] (additive); 273..287 = 0.  4 units per 256-thread block.
// ---------------------------------------------------------------------------
extern "C" __global__ __launch_bounds__(256) void deepfm_prep(
    const float* __restrict__ Wm, const float* __restrict__ bm,
    const float* __restrict__ Wu, const float* __restrict__ bu,
    const float* __restrict__ W1, const float* __restrict__ W2,
    const float* __restrict__ b3, char* __restrict__ ws) {
  const int unit = blockIdx.x * 4 + (threadIdx.x >> 6);
  if (unit >= 897) return;
  const int l = threadIdx.x & 63;
  const int fi = l & 15, q = l >> 4;
  unsigned short h[8];
  if (unit < 576) {                      // towers: 2 x 16 kg x 18 ft
    const int t = unit / 288, rem = unit % 288;
    const int kg = rem / 18, ft = rem % 18;
    const float* W = t ? Wu : Wm;
    char* outp = ws + (t ? WS_WUF : WS_WMF);
    const int f = ft * 16 + fi;
#pragma unroll
    for (int e = 0; e < 8; ++e) {
      const int k = kg * 32 + q * 8 + e;
      float val;
      if (f < 256) val = W[k * 257 + f];
      else if (f < 272) {
        float s = 0.f;
#pragma unroll
        for (int i = 0; i < 16; ++i) s += W[k * 257 + i * 16 + (f - 256)];
        val = s;
      } else if (f == 272) val = W[k * 257 + 256];
      else val = 0.f;
      h[e] = f2bf(val);
    }
    uint4 o;
    o.x = h[0] | ((unsigned)h[1] << 16); o.y = h[2] | ((unsigned)h[3] << 16);
    o.z = h[4] | ((unsigned)h[5] << 16); o.w = h[6] | ((unsigned)h[7] << 16);
    *(uint4*)(outp + (((kg * 18 + ft) * 64 + l) << 4)) = o;
  } else if (unit < 832) {               // W1: 16 kg x 16 ft
    const int bb = unit - 576;
    const int kg = bb / 16, ft = bb % 16;
    const int f = ft * 16 + fi;
#pragma unroll
    for (int e = 0; e < 8; ++e) h[e] = f2bf(W1[(kg * 32 + q * 8 + e) * 256 + f]);
    uint4 o;
    o.x = h[0] | ((unsigned)h[1] << 16); o.y = h[2] | ((unsigned)h[3] << 16);
    o.z = h[4] | ((unsigned)h[5] << 16); o.w = h[6] | ((unsigned)h[7] << 16);
    *(uint4*)(ws + WS_W1F + (((kg * 16 + ft) * 64 + l) << 4)) = o;
  } else if (unit < 896) {               // W2: 8 kg x 8 ft
    const int bb = unit - 832;
    const int kg = bb / 8, ft = bb % 8;
    const int f = ft * 16 + fi;
#pragma unroll
    for (int e = 0; e < 8; ++e) h[e] = f2bf(W2[(kg * 32 + q * 8 + e) * 128 + f]);
    uint4 o;
    o.x = h[0] | ((unsigned)h[1] << 16); o.y = h[2] | ((unsigned)h[3] << 16);
    o.z = h[4] | ((unsigned)h[5] << 16); o.w = h[6] | ((unsigned)h[7] << 16);
    *(uint4*)(ws + WS_W2F + (((kg * 8 + ft) * 64 + l) << 4)) = o;
  } else {                               // bias aux
    float* aux = (float*)(ws + WS_BIAS);
    if (l < 16) {
      float s = 0.f;
      for (int i = 0; i < 16; ++i) s += bm[i * 16 + l];
      aux[l] = s;
    } else if (l < 32) {
      const int k = l - 16;
      float s = 0.f;
      for (int i = 0; i < 16; ++i) s += bu[i * 16 + k];
      aux[l] = s;
    } else if (l == 32) {
      aux[32] = bm[256] + bu[256] + b3[0];
    }
  }
}

// ---------------------------------------------------------------------------
// Main fused kernel. 32 rows/block, 8 waves.
// Phase 1: tw = w>>2 (tower), wi = w&3. Wave owns ft tiles {wi*4..wi*4+3},
// rt 0..1, plus aux tile axi=wi&1 (0: ft16 FM-sums, 1: ft17 additive) at
// rt=wi>>1. K is processed in 2 staged halves (256 cols each).
// ---------------------------------------------------------------------------
extern "C" __global__ __attribute__((amdgpu_waves_per_eu(2, 4)))
__launch_bounds__(NTH) void deepfm_main(
    const float* __restrict__ movie, const float* __restrict__ user,
    const float* __restrict__ bm, const float* __restrict__ bu,
    const float* __restrict__ b1, const float* __restrict__ b2,
    const float* __restrict__ W3, const char* __restrict__ ws,
    float* __restrict__ out) {
  extern __shared__ __align__(16) char lds[];
  char* const bstage    = lds + L_BST;     // 64 rows (both towers), half K
  char* const densefrag = lds + L_DENSE;   // [16kg][2rt][64][16]
  char* const h1frag    = lds + L_BST;     // phases 2/3 (aliases bstage)
  float* const fmbuf    = (float*)(lds + L_FM);   // [2][32][17]
  float* const addbuf   = (float*)(lds + L_ADD);  // [2][32]
  float* const outpart  = (float*)(lds + L_OUT);

  const int tid = threadIdx.x;
  const int w   = tid >> 6;
  const int l   = tid & 63;
  const int cn  = l & 15;
  const int q   = l >> 4;
  const int row0 = blockIdx.x * RB;

  const int tw   = w >> 2;         // tower this wave computes in phase 1
  const int wi   = w & 3;
  const int axi  = wi & 1;         // 0: ft16 (FM col sums), 1: ft17 (additive)
  const int axrt = wi >> 1;        // rt tile for aux MFMA

  const f32x4 zz = {0.f, 0.f, 0.f, 0.f};
  const float* auxb = (const float*)(ws + WS_BIAS);

  // ---------------- Phase 1: both towers in parallel, K in 2 staged halves
  {
    const char* WF = ws + (tw ? WS_WUF : WS_WMF);
    const char* brow = bstage + tw * 32 * BPITCH;
    f32x4 a0r0 = zz, a0r1 = zz, a1r0 = zz, a1r1 = zz;
    f32x4 a2r0 = zz, a2r1 = zz, a3r0 = zz, a3r1 = zz;
    f32x4 axc = zz;

    for (int h = 0; h < 2; ++h) {
      if (h) __syncthreads();      // half-0 reads done before overwrite
      // stage 64 rows x 256 cols (half K) fp32 -> bf16, coalesced
#pragma unroll
      for (int p = 0; p < 8; ++p) {
        const int idx = p * 512 + tid;     // float4 id
        const int r = idx >> 6, f4 = idx & 63;
        const float* src = (r >= 32) ? user : movie;
        const float4 v = *(const float4*)(src + (size_t)(row0 + (r & 31)) * 512 +
                                          h * 256 + f4 * 4);
        uint2 o;
        o.x = f2bf(v.x) | ((unsigned)f2bf(v.y) << 16);
        o.y = f2bf(v.z) | ((unsigned)f2bf(v.w) << 16);
        *(uint2*)(bstage + r * BPITCH + f4 * 8) = o;
      }
      __syncthreads();

#pragma unroll 4
      for (int kgl = 0; kgl < 8; ++kgl) {
        const int kg = h * 8 + kgl;
        const bf16x8 bf0 = *(const bf16x8*)(brow + cn * BPITCH + kgl * 64 + q * 16);
        const bf16x8 bf1 = *(const bf16x8*)(brow + (16 + cn) * BPITCH + kgl * 64 + q * 16);
        const bf16x8 A0 = *(const bf16x8*)(WF + (((kg * 18 + wi * 4 + 0) * 64 + l) << 4));
        const bf16x8 A1 = *(const bf16x8*)(WF + (((kg * 18 + wi * 4 + 1) * 64 + l) << 4));
        const bf16x8 A2 = *(const bf16x8*)(WF + (((kg * 18 + wi * 4 + 2) * 64 + l) << 4));
        const bf16x8 A3 = *(const bf16x8*)(WF + (((kg * 18 + wi * 4 + 3) * 64 + l) << 4));
        const bf16x8 AX = *(const bf16x8*)(WF + (((kg * 18 + 16 + axi) * 64 + l) << 4));
        a0r0 = mfma_bf16(A0, bf0, a0r0);  a0r1 = mfma_bf16(A0, bf1, a0r1);
        a1r0 = mfma_bf16(A1, bf0, a1r0);  a1r1 = mfma_bf16(A1, bf1, a1r1);
        a2r0 = mfma_bf16(A2, bf0, a2r0);  a2r1 = mfma_bf16(A2, bf1, a2r1);
        a3r0 = mfma_bf16(A3, bf0, a3r0);  a3r1 = mfma_bf16(A3, bf1, a3r1);
        axc  = mfma_bf16(AX, axrt ? bf1 : bf0, axc);
      }
    }

    // writeback dense feats (+tower bias, no relu) into densefrag
    const float* bt = tw ? bu : bm;
    const f32x4 accA[4][2] = {{a0r0, a0r1}, {a1r0, a1r1}, {a2r0, a2r1}, {a3r0, a3r1}};
#pragma unroll
    for (int s = 0; s < 4; ++s) {
      const int ft = wi * 4 + s;
      const int fb = ft * 16 + q * 4;
      const float g0 = bt[fb], g1 = bt[fb + 1], g2 = bt[fb + 2], g3 = bt[fb + 3];
      const int kd = tw * 256 + fb;
      const int kgd = kd >> 5, qd = (kd >> 3) & 3, ed = kd & 4;
#pragma unroll
      for (int rt = 0; rt < 2; ++rt) {
        const f32x4 v = accA[s][rt];
        uint2 p;
        p.x = f2bf(v[0] + g0) | ((unsigned)f2bf(v[1] + g1) << 16);
        p.y = f2bf(v[2] + g2) | ((unsigned)f2bf(v[3] + g3) << 16);
        *(uint2*)(densefrag + (((kgd * 2 + rt) * 64 + qd * 16 + cn) << 4) +
                  (ed ? 8 : 0)) = p;
      }
    }

    // aux writeback: FM sums -> fmbuf (k = 4q+reg), additive row0 -> addbuf
    if (axi == 0) {
#pragma unroll
      for (int reg = 0; reg < 4; ++reg)
        fmbuf[(tw * 32 + axrt * 16 + cn) * 17 + (q * 4 + reg)] = axc[reg];
    } else if (q == 0) {
      addbuf[tw * 32 + axrt * 16 + cn] = axc[0];
    }
  }

  __syncthreads();   // densefrag + fmbuf/addbuf complete; bstage dead

  // ---------------- FM epilogue: out_partial = <ms+bms, us+bus> + additive
  if (tid < 32) {
    float p = 0.f;
#pragma unroll
    for (int k = 0; k < 16; ++k)
      p += (fmbuf[tid * 17 + k] + auxb[k]) *
           (fmbuf[(32 + tid) * 17 + k] + auxb[16 + k]);
    outpart[tid] = p + addbuf[tid] + addbuf[32 + tid] + auxb[32];
  }

  // ---------------- Phase 2: h1 = relu(all_dense @ W1 + b1)
  {
    const char* W1F = ws + WS_W1F;
    f32x4 a00 = zz, a01 = zz, a10 = zz, a11 = zz;
#pragma unroll 4
    for (int kg = 0; kg < 16; ++kg) {
      const bf16x8 b0  = *(const bf16x8*)(densefrag + (((kg * 2 + 0) * 64 + l) << 4));
      const bf16x8 b1f = *(const bf16x8*)(densefrag + (((kg * 2 + 1) * 64 + l) << 4));
      const bf16x8 a0 = *(const bf16x8*)(W1F + (((kg * 16 + w) * 64 + l) << 4));
      const bf16x8 a1 = *(const bf16x8*)(W1F + (((kg * 16 + w + 8) * 64 + l) << 4));
      a00 = mfma_bf16(a0, b0,  a00);
      a01 = mfma_bf16(a0, b1f, a01);
      a10 = mfma_bf16(a1, b0,  a10);
      a11 = mfma_bf16(a1, b1f, a11);
    }
    const f32x4 accA[2][2] = {{a00, a01}, {a10, a11}};
#pragma unroll
    for (int s = 0; s < 2; ++s) {
      const int ft = w + s * 8;
      const int fb = ft * 16 + q * 4;
      const float g0 = b1[fb], g1 = b1[fb + 1], g2 = b1[fb + 2], g3 = b1[fb + 3];
      const int kgd = fb >> 5, qd = (fb >> 3) & 3, ed = fb & 4;
#pragma unroll
      for (int rt = 0; rt < 2; ++rt) {
        const f32x4 v = accA[s][rt];
        uint2 p;
        p.x = f2bf(fmaxf(v[0] + g0, 0.f)) | ((unsigned)f2bf(fmaxf(v[1] + g1, 0.f)) << 16);
        p.y = f2bf(fmaxf(v[2] + g2, 0.f)) | ((unsigned)f2bf(fmaxf(v[3] + g3, 0.f)) << 16);
        *(uint2*)(h1frag + (((kgd * 2 + rt) * 64 + qd * 16 + cn) << 4) +
                  (ed ? 8 : 0)) = p;
      }
    }
  }

  __syncthreads();   // h1frag complete; outpart (FM) written

  // ---------------- Phase 3: h2 = relu(h1 @ W2 + b2); out = h2 @ W3 (+FM)
  {
    const char* W2F = ws + WS_W2F;
    f32x4 d0 = zz, d1 = zz;
#pragma unroll 4
    for (int kg = 0; kg < 8; ++kg) {
      const bf16x8 b0  = *(const bf16x8*)(h1frag + (((kg * 2 + 0) * 64 + l) << 4));
      const bf16x8 b1f = *(const bf16x8*)(h1frag + (((kg * 2 + 1) * 64 + l) << 4));
      const bf16x8 a0 = *(const bf16x8*)(W2F + (((kg * 8 + w) * 64 + l) << 4));
      d0 = mfma_bf16(a0, b0,  d0);
      d1 = mfma_bf16(a0, b1f, d1);
    }
    const int fb = w * 16 + q * 4;       // h2 feature strip (0..127)
    float bb[4], ww[4];
#pragma unroll
    for (int i = 0; i < 4; ++i) { bb[i] = b2[fb + i]; ww[i] = W3[fb + i]; }
    const f32x4 acc3[2] = {d0, d1};
#pragma unroll
    for (int rt = 0; rt < 2; ++rt) {
      float p = 0.f;
#pragma unroll
      for (int reg = 0; reg < 4; ++reg)
        p += fmaxf(acc3[rt][reg] + bb[reg], 0.f) * ww[reg];
      p += __shfl_xor(p, 16, 64);
      p += __shfl_xor(p, 32, 64);
      if (l < 16) atomicAdd(&outpart[rt * 16 + cn], p);
    }
  }

  __syncthreads();
  if (tid < 32) out[row0 + tid] = outpart[tid];
}

// ---------------------------------------------------------------------------
extern "C" void kernel_launch(void* const* d_in, const int* in_sizes, int n_in,
                              void* d_out, int out_size, void* d_ws, size_t ws_size,
                              hipStream_t stream) {
  const float* movie = (const float*)d_in[0];
  const float* user  = (const float*)d_in[1];
  const float* Wm = (const float*)d_in[2];
  const float* bm = (const float*)d_in[3];
  const float* Wu = (const float*)d_in[4];
  const float* bu = (const float*)d_in[5];
  const float* W1 = (const float*)d_in[6];
  const float* b1 = (const float*)d_in[7];
  const float* W2 = (const float*)d_in[8];
  const float* b2 = (const float*)d_in[9];
  const float* W3 = (const float*)d_in[10];
  const float* b3 = (const float*)d_in[11];
  char* ws = (char*)d_ws;
  float* out = (float*)d_out;

  // allow >64KB dynamic LDS (idempotent, capture-safe)
  (void)hipFuncSetAttribute((const void*)deepfm_main,
                            hipFuncAttributeMaxDynamicSharedMemorySize, LDSB);

  deepfm_prep<<<225, 256, 0, stream>>>(Wm, bm, Wu, bu, W1, W2, b3, ws);
  deepfm_main<<<512, NTH, LDSB, stream>>>(movie, user, bm, bu, b1, b2, W3, ws, out);
}

// Round 11
// 130.040 us; speedup vs baseline: 1.1775x; 1.1775x over previous
//
#include <hip/hip_runtime.h>

// DeepFM fused kernel for MI355X (gfx950) — round 11.
// R9 structure, but RB 32->64 and NTH 512->1024 (16 waves, 1 block/CU =
// same 16 waves/CU as R9). Rationale: R7/R9 both sit at 42 us with A-frag
// L2 traffic (~492 MB) as the invariant binder (~19 B/cyc/CU served, all
// pipes idle). Doubling rows per block halves A bytes per row: each A-frag
// now feeds 4 rt-tiles (phase-1: 3 A-loads + 4 LDS B-reads -> 9 MFMAs).
// R10's waves_per_eu attribute reverted (regression).
//  - prep: repack Wm/Wu (augmented: 16 FM col-sum feats + additive feat),
//    W1, W2 into bf16 MFMA A-frag order in ws; bias aux. 256-thr blocks.
//  - main: 256 blocks x 1024 thr (16 waves), 64 rows/block, 1 block/CU
//    (dynamic LDS 142592 B). Tower-parallel phase 1 (waves 0-7 movie,
//    8-15 user), B staged in two half-K rounds, FM via padded LDS buf.

#define NTH 1024
#define RB  64

typedef __bf16 bf16x8 __attribute__((ext_vector_type(8)));
typedef float  f32x4  __attribute__((ext_vector_type(4)));

// workspace layout (bytes)
#define WS_WMF  0            // movie tower A-frags [16 kg][18 ft][64][16B]
#define WS_WUF  294912
#define WS_W1F  589824       // [16 kg][16 ft][64][16B]
#define WS_W2F  851968       // [8 kg][8 ft][64][16B]
#define WS_BIAS 917504       // fp32 bms[16] bus[16] badd

// LDS layout (bytes)
#define BPITCH  528          // 256 bf16 (half K) + 16B pad per row
#define L_BST   0            // bstage: 128 rows x 528 = 67584 (h1frag aliases)
#define L_DENSE 67584        // densefrag [16kg][4rt][64][16] = 65536
#define L_FM    133120       // fmbuf [2][64][17] f32 = 8704
#define L_ADD   141824       // addbuf [2][64] f32 = 512
#define L_OUT   142336       // outpart[64] f32 = 256
#define LDSB    142592

__device__ __forceinline__ unsigned short f2bf(float f) {
  unsigned u = __builtin_bit_cast(unsigned, f);
  u += 0x7FFFu + ((u >> 16) & 1u);           // RNE
  return (unsigned short)(u >> 16);
}

__device__ __forceinline__ f32x4 mfma_bf16(bf16x8 a, bf16x8 b, f32x4 c) {
  return __builtin_amdgcn_mfma_f32_16x16x32_bf16(a, b, c, 0, 0, 0);
}

// ---------------------------------------------------------------------------
// Prep: fragment-ordered bf16 weights + bias aux. Tower features:
// f<256 raw col f; 256..271 = sum_i W[:, i*16+(f-256)] (FM col sums);
// 272 = W[:,256] (additive); 273..287 = 0.  4 units per 256-thread block.
// ---------------------------------------------------------------------------
extern "C" __global__ __launch_bounds__(256) void deepfm_prep(
    const float* __restrict__ Wm, const float* __restrict__ bm,
    const float* __restrict__ Wu, const float* __restrict__ bu,
    const float* __restrict__ W1, const float* __restrict__ W2,
    const float* __restrict__ b3, char* __restrict__ ws) {
  const int unit = blockIdx.x * 4 + (threadIdx.x >> 6);
  if (unit >= 897) return;
  const int l = threadIdx.x & 63;
  const int fi = l & 15, q = l >> 4;
  unsigned short h[8];
  if (unit < 576) {                      // towers: 2 x 16 kg x 18 ft
    const int t = unit / 288, rem = unit % 288;
    const int kg = rem / 18, ft = rem % 18;
    const float* W = t ? Wu : Wm;
    char* outp = ws + (t ? WS_WUF : WS_WMF);
    const int f = ft * 16 + fi;
#pragma unroll
    for (int e = 0; e < 8; ++e) {
      const int k = kg * 32 + q * 8 + e;
      float val;
      if (f < 256) val = W[k * 257 + f];
      else if (f < 272) {
        float s = 0.f;
#pragma unroll
        for (int i = 0; i < 16; ++i) s += W[k * 257 + i * 16 + (f - 256)];
        val = s;
      } else if (f == 272) val = W[k * 257 + 256];
      else val = 0.f;
      h[e] = f2bf(val);
    }
    uint4 o;
    o.x = h[0] | ((unsigned)h[1] << 16); o.y = h[2] | ((unsigned)h[3] << 16);
    o.z = h[4] | ((unsigned)h[5] << 16); o.w = h[6] | ((unsigned)h[7] << 16);
    *(uint4*)(outp + (((kg * 18 + ft) * 64 + l) << 4)) = o;
  } else if (unit < 832) {               // W1: 16 kg x 16 ft
    const int bb = unit - 576;
    const int kg = bb / 16, ft = bb % 16;
    const int f = ft * 16 + fi;
#pragma unroll
    for (int e = 0; e < 8; ++e) h[e] = f2bf(W1[(kg * 32 + q * 8 + e) * 256 + f]);
    uint4 o;
    o.x = h[0] | ((unsigned)h[1] << 16); o.y = h[2] | ((unsigned)h[3] << 16);
    o.z = h[4] | ((unsigned)h[5] << 16); o.w = h[6] | ((unsigned)h[7] << 16);
    *(uint4*)(ws + WS_W1F + (((kg * 16 + ft) * 64 + l) << 4)) = o;
  } else if (unit < 896) {               // W2: 8 kg x 8 ft
    const int bb = unit - 832;
    const int kg = bb / 8, ft = bb % 8;
    const int f = ft * 16 + fi;
#pragma unroll
    for (int e = 0; e < 8; ++e) h[e] = f2bf(W2[(kg * 32 + q * 8 + e) * 128 + f]);
    uint4 o;
    o.x = h[0] | ((unsigned)h[1] << 16); o.y = h[2] | ((unsigned)h[3] << 16);
    o.z = h[4] | ((unsigned)h[5] << 16); o.w = h[6] | ((unsigned)h[7] << 16);
    *(uint4*)(ws + WS_W2F + (((kg * 8 + ft) * 64 + l) << 4)) = o;
  } else {                               // bias aux
    float* aux = (float*)(ws + WS_BIAS);
    if (l < 16) {
      float s = 0.f;
      for (int i = 0; i < 16; ++i) s += bm[i * 16 + l];
      aux[l] = s;
    } else if (l < 32) {
      const int k = l - 16;
      float s = 0.f;
      for (int i = 0; i < 16; ++i) s += bu[i * 16 + k];
      aux[l] = s;
    } else if (l == 32) {
      aux[32] = bm[256] + bu[256] + b3[0];
    }
  }
}

// ---------------------------------------------------------------------------
// Main fused kernel. 64 rows/block, 16 waves.
// Phase 1: tw = w>>3 (tower), wi = w&7. Wave owns ft tiles {wi*2, wi*2+1},
// rt 0..3, plus aux tile axi=wi&1 (0: ft16 FM-sums, 1: ft17 additive) at
// rt=wi>>1 (0..3). K processed in 2 staged halves (256 cols each).
// Phase 2: wave w owns ft=w (of 16), rt 0..3.
// Phase 3: wave w owns ft=w&7 (of 8), rt pair (w>>3)*2..+1.
// ---------------------------------------------------------------------------
extern "C" __global__ __launch_bounds__(NTH, 4) void deepfm_main(
    const float* __restrict__ movie, const float* __restrict__ user,
    const float* __restrict__ bm, const float* __restrict__ bu,
    const float* __restrict__ b1, const float* __restrict__ b2,
    const float* __restrict__ W3, const char* __restrict__ ws,
    float* __restrict__ out) {
  extern __shared__ __align__(16) char lds[];
  char* const bstage    = lds + L_BST;     // 128 rows (both towers), half K
  char* const densefrag = lds + L_DENSE;   // [16kg][4rt][64][16]
  char* const h1frag    = lds + L_BST;     // phases 2/3 (aliases bstage)
  float* const fmbuf    = (float*)(lds + L_FM);   // [2][64][17]
  float* const addbuf   = (float*)(lds + L_ADD);  // [2][64]
  float* const outpart  = (float*)(lds + L_OUT);

  const int tid = threadIdx.x;
  const int w   = tid >> 6;        // 0..15
  const int l   = tid & 63;
  const int cn  = l & 15;
  const int q   = l >> 4;
  const int row0 = blockIdx.x * RB;

  const int tw   = w >> 3;         // tower this wave computes in phase 1
  const int wi   = w & 7;
  const int axi  = wi & 1;         // 0: ft16 (FM col sums), 1: ft17 (additive)
  const int axrt = wi >> 1;        // rt tile (0..3) for aux MFMA

  const f32x4 zz = {0.f, 0.f, 0.f, 0.f};
  const float* auxb = (const float*)(ws + WS_BIAS);

  // ---------------- Phase 1: both towers in parallel, K in 2 staged halves
  {
    const char* WF = ws + (tw ? WS_WUF : WS_WMF);
    const char* brow = bstage + tw * 64 * BPITCH;
    f32x4 a0r0 = zz, a0r1 = zz, a0r2 = zz, a0r3 = zz;
    f32x4 a1r0 = zz, a1r1 = zz, a1r2 = zz, a1r3 = zz;
    f32x4 axc = zz;

    for (int h = 0; h < 2; ++h) {
      if (h) __syncthreads();      // half-0 reads done before overwrite
      // stage 128 rows x 256 cols (half K) fp32 -> bf16, coalesced
#pragma unroll
      for (int p = 0; p < 8; ++p) {
        const int idx = p * 1024 + tid;    // float4 id
        const int r = idx >> 6, f4 = idx & 63;
        const float* src = (r >= 64) ? user : movie;
        const float4 v = *(const float4*)(src + (size_t)(row0 + (r & 63)) * 512 +
                                          h * 256 + f4 * 4);
        uint2 o;
        o.x = f2bf(v.x) | ((unsigned)f2bf(v.y) << 16);
        o.y = f2bf(v.z) | ((unsigned)f2bf(v.w) << 16);
        *(uint2*)(bstage + r * BPITCH + f4 * 8) = o;
      }
      __syncthreads();

#pragma unroll 2
      for (int kgl = 0; kgl < 8; ++kgl) {
        const int kg = h * 8 + kgl;
        const bf16x8 bf0 = *(const bf16x8*)(brow + cn * BPITCH + kgl * 64 + q * 16);
        const bf16x8 bf1 = *(const bf16x8*)(brow + (16 + cn) * BPITCH + kgl * 64 + q * 16);
        const bf16x8 bf2 = *(const bf16x8*)(brow + (32 + cn) * BPITCH + kgl * 64 + q * 16);
        const bf16x8 bf3 = *(const bf16x8*)(brow + (48 + cn) * BPITCH + kgl * 64 + q * 16);
        const bf16x8 A0 = *(const bf16x8*)(WF + (((kg * 18 + wi * 2 + 0) * 64 + l) << 4));
        const bf16x8 A1 = *(const bf16x8*)(WF + (((kg * 18 + wi * 2 + 1) * 64 + l) << 4));
        const bf16x8 AX = *(const bf16x8*)(WF + (((kg * 18 + 16 + axi) * 64 + l) << 4));
        a0r0 = mfma_bf16(A0, bf0, a0r0);  a0r1 = mfma_bf16(A0, bf1, a0r1);
        a0r2 = mfma_bf16(A0, bf2, a0r2);  a0r3 = mfma_bf16(A0, bf3, a0r3);
        a1r0 = mfma_bf16(A1, bf0, a1r0);  a1r1 = mfma_bf16(A1, bf1, a1r1);
        a1r2 = mfma_bf16(A1, bf2, a1r2);  a1r3 = mfma_bf16(A1, bf3, a1r3);
        const bf16x8 bsel = (axrt == 0) ? bf0 : (axrt == 1) ? bf1
                          : (axrt == 2) ? bf2 : bf3;
        axc = mfma_bf16(AX, bsel, axc);
      }
    }

    // writeback dense feats (+tower bias, no relu) into densefrag
    const float* bt = tw ? bu : bm;
    const f32x4 accA[2][4] = {{a0r0, a0r1, a0r2, a0r3}, {a1r0, a1r1, a1r2, a1r3}};
#pragma unroll
    for (int s = 0; s < 2; ++s) {
      const int ft = wi * 2 + s;
      const int fb = ft * 16 + q * 4;
      const float g0 = bt[fb], g1 = bt[fb + 1], g2 = bt[fb + 2], g3 = bt[fb + 3];
      const int kd = tw * 256 + fb;
      const int kgd = kd >> 5, qd = (kd >> 3) & 3, ed = kd & 4;
#pragma unroll
      for (int rt = 0; rt < 4; ++rt) {
        const f32x4 v = accA[s][rt];
        uint2 p;
        p.x = f2bf(v[0] + g0) | ((unsigned)f2bf(v[1] + g1) << 16);
        p.y = f2bf(v[2] + g2) | ((unsigned)f2bf(v[3] + g3) << 16);
        *(uint2*)(densefrag + (((kgd * 4 + rt) * 64 + qd * 16 + cn) << 4) +
                  (ed ? 8 : 0)) = p;
      }
    }

    // aux writeback: FM sums -> fmbuf (k = 4q+reg), additive row0 -> addbuf
    if (axi == 0) {
#pragma unroll
      for (int reg = 0; reg < 4; ++reg)
        fmbuf[(tw * 64 + axrt * 16 + cn) * 17 + (q * 4 + reg)] = axc[reg];
    } else if (q == 0) {
      addbuf[tw * 64 + axrt * 16 + cn] = axc[0];
    }
  }

  __syncthreads();   // densefrag + fmbuf/addbuf complete; bstage dead

  // ---------------- FM epilogue: out_partial = <ms+bms, us+bus> + additive
  if (tid < 64) {
    float p = 0.f;
#pragma unroll
    for (int k = 0; k < 16; ++k)
      p += (fmbuf[tid * 17 + k] + auxb[k]) *
           (fmbuf[(64 + tid) * 17 + k] + auxb[16 + k]);
    outpart[tid] = p + addbuf[tid] + addbuf[64 + tid] + auxb[32];
  }

  // ---------------- Phase 2: h1 = relu(all_dense @ W1 + b1)
  {
    const char* W1F = ws + WS_W1F;
    f32x4 r0 = zz, r1 = zz, r2 = zz, r3 = zz;
#pragma unroll 4
    for (int kg = 0; kg < 16; ++kg) {
      const bf16x8 b0 = *(const bf16x8*)(densefrag + (((kg * 4 + 0) * 64 + l) << 4));
      const bf16x8 b1f = *(const bf16x8*)(densefrag + (((kg * 4 + 1) * 64 + l) << 4));
      const bf16x8 b2f = *(const bf16x8*)(densefrag + (((kg * 4 + 2) * 64 + l) << 4));
      const bf16x8 b3f = *(const bf16x8*)(densefrag + (((kg * 4 + 3) * 64 + l) << 4));
      const bf16x8 a0 = *(const bf16x8*)(W1F + (((kg * 16 + w) * 64 + l) << 4));
      r0 = mfma_bf16(a0, b0,  r0);
      r1 = mfma_bf16(a0, b1f, r1);
      r2 = mfma_bf16(a0, b2f, r2);
      r3 = mfma_bf16(a0, b3f, r3);
    }
    const f32x4 accA[4] = {r0, r1, r2, r3};
    const int fb = w * 16 + q * 4;
    const float g0 = b1[fb], g1 = b1[fb + 1], g2 = b1[fb + 2], g3 = b1[fb + 3];
    const int kgd = fb >> 5, qd = (fb >> 3) & 3, ed = fb & 4;
#pragma unroll
    for (int rt = 0; rt < 4; ++rt) {
      const f32x4 v = accA[rt];
      uint2 p;
      p.x = f2bf(fmaxf(v[0] + g0, 0.f)) | ((unsigned)f2bf(fmaxf(v[1] + g1, 0.f)) << 16);
      p.y = f2bf(fmaxf(v[2] + g2, 0.f)) | ((unsigned)f2bf(fmaxf(v[3] + g3, 0.f)) << 16);
      *(uint2*)(h1frag + (((kgd * 4 + rt) * 64 + qd * 16 + cn) << 4) +
                (ed ? 8 : 0)) = p;
    }
  }

  __syncthreads();   // h1frag complete; outpart (FM) visible for phase-3 atomics

  // ---------------- Phase 3: h2 = relu(h1 @ W2 + b2); out = h2 @ W3 (+FM)
  {
    const char* W2F = ws + WS_W2F;
    const int ftw = w & 7;           // h2 ft tile (0..7)
    const int rth = w >> 3;          // rt pair selector
    f32x4 d0 = zz, d1 = zz;
#pragma unroll 4
    for (int kg = 0; kg < 8; ++kg) {
      const bf16x8 b0 = *(const bf16x8*)(h1frag + (((kg * 4 + rth * 2 + 0) * 64 + l) << 4));
      const bf16x8 b1f = *(const bf16x8*)(h1frag + (((kg * 4 + rth * 2 + 1) * 64 + l) << 4));
      const bf16x8 a0 = *(const bf16x8*)(W2F + (((kg * 8 + ftw) * 64 + l) << 4));
      d0 = mfma_bf16(a0, b0,  d0);
      d1 = mfma_bf16(a0, b1f, d1);
    }
    const int fb = ftw * 16 + q * 4;     // h2 feature strip (0..127)
    float bb[4], ww[4];
#pragma unroll
    for (int i = 0; i < 4; ++i) { bb[i] = b2[fb + i]; ww[i] = W3[fb + i]; }
    const f32x4 acc3[2] = {d0, d1};
#pragma unroll
    for (int j = 0; j < 2; ++j) {
      const int rt = rth * 2 + j;
      float p = 0.f;
#pragma unroll
      for (int reg = 0; reg < 4; ++reg)
        p += fmaxf(acc3[j][reg] + bb[reg], 0.f) * ww[reg];
      p += __shfl_xor(p, 16, 64);
      p += __shfl_xor(p, 32, 64);
      if (l < 16) atomicAdd(&outpart[rt * 16 + cn], p);
    }
  }

  __syncthreads();
  if (tid < 64) out[row0 + tid] = outpart[tid];
}

// ---------------------------------------------------------------------------
extern "C" void kernel_launch(void* const* d_in, const int* in_sizes, int n_in,
                              void* d_out, int out_size, void* d_ws, size_t ws_size,
                              hipStream_t stream) {
  const float* movie = (const float*)d_in[0];
  const float* user  = (const float*)d_in[1];
  const float* Wm = (const float*)d_in[2];
  const float* bm = (const float*)d_in[3];
  const float* Wu = (const float*)d_in[4];
  const float* bu = (const float*)d_in[5];
  const float* W1 = (const float*)d_in[6];
  const float* b1 = (const float*)d_in[7];
  const float* W2 = (const float*)d_in[8];
  const float* b2 = (const float*)d_in[9];
  const float* W3 = (const float*)d_in[10];
  const float* b3 = (const float*)d_in[11];
  char* ws = (char*)d_ws;
  float* out = (float*)d_out;

  // allow >64KB dynamic LDS (idempotent, capture-safe)
  (void)hipFuncSetAttribute((const void*)deepfm_main,
                            hipFuncAttributeMaxDynamicSharedMemorySize, LDSB);

  deepfm_prep<<<225, 256, 0, stream>>>(Wm, bm, Wu, bu, W1, W2, b3, ws);
  deepfm_main<<<256, NTH, LDSB, stream>>>(movie, user, bm, bu, b1, b2, W3, ws, out);
}